// Round 1
// baseline (316.966 us; speedup 1.0000x reference)
//
#include <hip/hip_runtime.h>

// ---------------------------------------------------------------- constants
static constexpr int Bn   = 8;
static constexpr int S    = 1024;
static constexpr int FT   = 16;
static constexpr int FDZ  = 768;
static constexpr int INK  = 784;   // FDZ + FT
static constexpr int KP   = 800;   // padded K for dense GEMM (25 * 32)
static constexpr int FDEC = 1024;
static constexpr int M    = Bn * S;   // 8192 rows
static constexpr int H    = 16;
static constexpr int DKH  = 64;
static constexpr int FD   = 16;

typedef __bf16 bf16x8 __attribute__((ext_vector_type(8)));
typedef float  f32x4  __attribute__((ext_vector_type(4)));

__device__ __forceinline__ unsigned short f2b(float f) {
  unsigned int u = __float_as_uint(f);
  u = (u + 0x7fffu + ((u >> 16) & 1u)) >> 16;   // RNE
  return (unsigned short)u;
}

// ---------------------------------------------------------------- prep kernels
__global__ __launch_bounds__(256) void k_prep_xin(const float* __restrict__ z,
                                                  const float* __restrict__ rt,
                                                  unsigned short* __restrict__ xin) {
  int idx = blockIdx.x * 256 + threadIdx.x;
  if (idx >= M * KP) return;
  int m = idx / KP, c = idx - m * KP;
  float v = 0.f;
  if (c < FT)       v = rt[m * FT + c];
  else if (c < INK) v = z[(m >> 10) * FDZ + (c - FT)];
  xin[idx] = f2b(v);
}

__global__ __launch_bounds__(256) void k_cvt_pad(const float* __restrict__ src,
                                                 unsigned short* __restrict__ dst,
                                                 int R, int C, int Cp) {
  int idx = blockIdx.x * 256 + threadIdx.x;
  if (idx >= R * Cp) return;
  int r = idx / Cp, c = idx - r * Cp;
  dst[idx] = (c < C) ? f2b(src[(size_t)r * C + c]) : (unsigned short)0;
}

__global__ __launch_bounds__(256) void k_b3(const float* __restrict__ bq,
                                            const float* __restrict__ bk,
                                            const float* __restrict__ bv,
                                            float* __restrict__ b3) {
  int i = blockIdx.x * 256 + threadIdx.x;
  if (i < 1024)      b3[i] = bq[i];
  else if (i < 2048) b3[i] = bk[i - 1024];
  else if (i < 3072) b3[i] = bv[i - 2048];
}

// ---------------------------------------------------------------- GEMM (C = A @ B^T + bias)
// A: [M][lda] bf16, Bw: [N][ldb] bf16 row-major (weights), K = reduction length.
// EPI 0: Cf[row*N+col] = acc + bias                      (dense -> x fp32)
// EPI 1: Cb[row*N+col] = bf16(acc + bias)                (qkv)
// EPI 2: xv = Cf[..] + acc + bias; Cf = xv; Cb = bf16(xv) (residual out-proj)
template<int EPI>
__global__ __launch_bounds__(256) void k_gemm(const unsigned short* __restrict__ A, int lda,
                                              const unsigned short* __restrict__ Bw, int ldb,
                                              int K, int N,
                                              const float* __restrict__ bias,
                                              float* __restrict__ Cf,
                                              unsigned short* __restrict__ Cb) {
  __shared__ unsigned short As[128][40];
  __shared__ unsigned short Bs[128][40];
  const int tid = threadIdx.x;
  const int lane = tid & 63, wid = tid >> 6;
  const int wr = wid >> 1, wc = wid & 1;
  const int m0 = blockIdx.x * 128, n0 = blockIdx.y * 128;
  const int lr = lane & 15, lg = lane >> 4;

  f32x4 acc[4][4];
  for (int i = 0; i < 4; i++)
    for (int j = 0; j < 4; j++)
      for (int e = 0; e < 4; e++) acc[i][j][e] = 0.f;

  for (int k0 = 0; k0 < K; k0 += 32) {
    for (int it = 0; it < 2; ++it) {
      int c = tid + it * 256;                // 0..511
      int row = c >> 2, cc = (c & 3) << 3;
      *reinterpret_cast<uint4*>(&As[row][cc]) =
          *reinterpret_cast<const uint4*>(&A[(size_t)(m0 + row) * lda + k0 + cc]);
      *reinterpret_cast<uint4*>(&Bs[row][cc]) =
          *reinterpret_cast<const uint4*>(&Bw[(size_t)(n0 + row) * ldb + k0 + cc]);
    }
    __syncthreads();
    bf16x8 af[4], bf[4];
    for (int mi = 0; mi < 4; mi++)
      af[mi] = *reinterpret_cast<const bf16x8*>(&As[wr * 64 + mi * 16 + lr][lg * 8]);
    for (int ni = 0; ni < 4; ni++)
      bf[ni] = *reinterpret_cast<const bf16x8*>(&Bs[wc * 64 + ni * 16 + lr][lg * 8]);
    for (int mi = 0; mi < 4; mi++)
      for (int ni = 0; ni < 4; ni++)
        acc[mi][ni] = __builtin_amdgcn_mfma_f32_16x16x32_bf16(af[mi], bf[ni], acc[mi][ni], 0, 0, 0);
    __syncthreads();
  }

  for (int mi = 0; mi < 4; mi++)
    for (int ni = 0; ni < 4; ni++) {
      int col = n0 + wc * 64 + ni * 16 + lr;
      float bv = bias ? bias[col] : 0.f;
      for (int j = 0; j < 4; j++) {
        int row = m0 + wr * 64 + mi * 16 + lg * 4 + j;
        float v = acc[mi][ni][j] + bv;
        if constexpr (EPI == 0) {
          Cf[(size_t)row * N + col] = v;
        } else if constexpr (EPI == 1) {
          Cb[(size_t)row * N + col] = f2b(v);
        } else {
          size_t o = (size_t)row * N + col;
          float xv = Cf[o] + v;
          Cf[o] = xv;
          Cb[o] = f2b(xv);
        }
      }
    }
}

// ---------------------------------------------------------------- LayerNorm (per row of 1024)
__global__ __launch_bounds__(256) void k_ln(const float* __restrict__ x,
                                            const float* __restrict__ g,
                                            const float* __restrict__ bta,
                                            unsigned short* __restrict__ xn) {
  int row = blockIdx.x;
  int tid = threadIdx.x;
  const float4 v = *reinterpret_cast<const float4*>(&x[(size_t)row * 1024 + tid * 4]);
  float s = v.x + v.y + v.z + v.w;
  float q = v.x * v.x + v.y * v.y + v.z * v.z + v.w * v.w;
  for (int off = 32; off; off >>= 1) { s += __shfl_down(s, off); q += __shfl_down(q, off); }
  __shared__ float ss[4], qq[4];
  int wid = tid >> 6, lane = tid & 63;
  if (lane == 0) { ss[wid] = s; qq[wid] = q; }
  __syncthreads();
  float St = ss[0] + ss[1] + ss[2] + ss[3];
  float Qt = qq[0] + qq[1] + qq[2] + qq[3];
  float mu  = St * (1.f / 1024.f);
  float var = Qt * (1.f / 1024.f) - mu * mu;
  float rstd = rsqrtf(var + 1e-6f);
  int c = tid * 4;
  unsigned short o[4];
  o[0] = f2b(g[c + 0] * (v.x - mu) * rstd + bta[c + 0]);
  o[1] = f2b(g[c + 1] * (v.y - mu) * rstd + bta[c + 1]);
  o[2] = f2b(g[c + 2] * (v.z - mu) * rstd + bta[c + 2]);
  o[3] = f2b(g[c + 3] * (v.w - mu) * rstd + bta[c + 3]);
  *reinterpret_cast<uint2*>(&xn[(size_t)row * 1024 + c]) = *reinterpret_cast<uint2*>(o);
}

// ---------------------------------------------------------------- flash attention
// grid: (B*H, S/128); 4 waves x 32 q-rows. K/V^T staged in LDS; P via per-wave LDS.
__global__ __launch_bounds__(256) void k_attn(const unsigned short* __restrict__ qkv,
                                              unsigned short* __restrict__ o) {
  __shared__ unsigned short Ks[64][72];
  __shared__ unsigned short Vt[64][72];      // Vt[d][key]
  __shared__ unsigned short Pl[4][32][72];
  const int tid = threadIdx.x, lane = tid & 63, w = tid >> 6;
  const int bh = blockIdx.x, b = bh >> 4, h = bh & 15;
  const int q0 = blockIdx.y * 128;
  const int lr = lane & 15, lg = lane >> 4;
  const float slope = exp2f(-0.5f * (float)(h + 1));

  bf16x8 qf[2][2];
  for (int qm = 0; qm < 2; qm++) {
    int row = q0 + w * 32 + qm * 16 + lr;
    const unsigned short* qp = &qkv[(size_t)(b * 1024 + row) * 3072 + h * 64];
    for (int kk = 0; kk < 2; kk++)
      qf[qm][kk] = *reinterpret_cast<const bf16x8*>(qp + kk * 32 + lg * 8);
  }

  float mrun[2][4], lrun[2][4];
  f32x4 accO[2][4];
  for (int qm = 0; qm < 2; qm++)
    for (int j = 0; j < 4; j++) { mrun[qm][j] = -3.0e38f; lrun[qm][j] = 0.f; }
  for (int qm = 0; qm < 2; qm++)
    for (int dn = 0; dn < 4; dn++)
      for (int e = 0; e < 4; e++) accO[qm][dn][e] = 0.f;

  const int nt = (q0 + 128) >> 6;
  for (int kt = 0; kt < nt; ++kt) {
    const int kb = kt << 6;
    for (int it = 0; it < 2; ++it) {
      int c = tid + it * 256;               // 0..511
      int row = c >> 3, c8 = (c & 7) << 3;
      const size_t base = (size_t)(b * 1024 + kb + row) * 3072 + h * 64;
      *reinterpret_cast<uint4*>(&Ks[row][c8]) =
          *reinterpret_cast<const uint4*>(&qkv[base + 1024 + c8]);
      uint4 vv = *reinterpret_cast<const uint4*>(&qkv[base + 2048 + c8]);
      const unsigned short* vs = reinterpret_cast<const unsigned short*>(&vv);
      for (int j = 0; j < 8; j++) Vt[c8 + j][row] = vs[j];
    }
    __syncthreads();

    for (int qm = 0; qm < 2; qm++) {
      f32x4 sf[4];
      for (int kn = 0; kn < 4; kn++) {
        f32x4 zz;
        for (int e = 0; e < 4; e++) zz[e] = 0.f;
        bf16x8 kf0 = *reinterpret_cast<const bf16x8*>(&Ks[kn * 16 + lr][lg * 8]);
        bf16x8 kf1 = *reinterpret_cast<const bf16x8*>(&Ks[kn * 16 + lr][32 + lg * 8]);
        zz = __builtin_amdgcn_mfma_f32_16x16x32_bf16(qf[qm][0], kf0, zz, 0, 0, 0);
        zz = __builtin_amdgcn_mfma_f32_16x16x32_bf16(qf[qm][1], kf1, zz, 0, 0, 0);
        sf[kn] = zz;
      }
      for (int j = 0; j < 4; j++) {
        int row_abs = q0 + w * 32 + qm * 16 + lg * 4 + j;
        float sc[4];
        float rm = -3.0e38f;
        for (int kn = 0; kn < 4; kn++) {
          int col = kb + kn * 16 + lr;
          float v = sf[kn][j] * 0.125f + slope * (float)col;
          if (col > row_abs) v = -1.0e9f;
          sc[kn] = v;
          rm = fmaxf(rm, v);
        }
        for (int off = 1; off < 16; off <<= 1) rm = fmaxf(rm, __shfl_xor(rm, off));
        float mnew = fmaxf(mrun[qm][j], rm);
        float f = expf(mrun[qm][j] - mnew);
        float rs = 0.f;
        int prow = qm * 16 + lg * 4 + j;
        for (int kn = 0; kn < 4; kn++) {
          float pv = expf(sc[kn] - mnew);
          rs += pv;
          Pl[w][prow][kn * 16 + lr] = f2b(pv);
        }
        for (int off = 1; off < 16; off <<= 1) rs += __shfl_xor(rs, off);
        lrun[qm][j] = lrun[qm][j] * f + rs;
        mrun[qm][j] = mnew;
        for (int dn = 0; dn < 4; dn++) accO[qm][dn][j] *= f;
      }
    }
    __syncthreads();   // P visible to own wave (ordering) + Ks/Vt still needed below

    for (int qm = 0; qm < 2; qm++)
      for (int ks = 0; ks < 2; ks++) {
        bf16x8 pa = *reinterpret_cast<const bf16x8*>(&Pl[w][qm * 16 + lr][ks * 32 + lg * 8]);
        for (int dn = 0; dn < 4; dn++) {
          bf16x8 vb = *reinterpret_cast<const bf16x8*>(&Vt[dn * 16 + lr][ks * 32 + lg * 8]);
          accO[qm][dn] = __builtin_amdgcn_mfma_f32_16x16x32_bf16(pa, vb, accO[qm][dn], 0, 0, 0);
        }
      }
    __syncthreads();   // protect Ks/Vt before next stage
  }

  for (int qm = 0; qm < 2; qm++)
    for (int dn = 0; dn < 4; dn++)
      for (int j = 0; j < 4; j++) {
        int row = q0 + w * 32 + qm * 16 + lg * 4 + j;
        int d = dn * 16 + lr;
        float ov = accO[qm][dn][j] / lrun[qm][j];
        o[(size_t)(b * 1024 + row) * 1024 + h * 64 + d] = f2b(ov);
      }
}

// ---------------------------------------------------------------- decode GEMM (N=16) + transpose
__global__ __launch_bounds__(256) void k_dec(const unsigned short* __restrict__ xb,
                                             const unsigned short* __restrict__ dw,
                                             const float* __restrict__ db,
                                             float* __restrict__ out) {
  const int tid = threadIdx.x, lane = tid & 63, w = tid >> 6;
  const int lr = lane & 15, lg = lane >> 4;
  const int sb = blockIdx.x * 4 + w;        // 0..511
  const int r0 = sb * 16;
  f32x4 acc;
  for (int e = 0; e < 4; e++) acc[e] = 0.f;
  const unsigned short* arow = &xb[(size_t)(r0 + lr) * 1024];
  const unsigned short* brow = &dw[(size_t)lr * 1024];
  for (int k0 = 0; k0 < 1024; k0 += 32) {
    bf16x8 af = *reinterpret_cast<const bf16x8*>(arow + k0 + lg * 8);
    bf16x8 bf = *reinterpret_cast<const bf16x8*>(brow + k0 + lg * 8);
    acc = __builtin_amdgcn_mfma_f32_16x16x32_bf16(af, bf, acc, 0, 0, 0);
  }
  const int b = r0 >> 10;
  const int sl = (r0 & 1023) + lg * 4;
  float bias = db[lr];
  float4 res;
  res.x = acc[0] + bias; res.y = acc[1] + bias; res.z = acc[2] + bias; res.w = acc[3] + bias;
  *reinterpret_cast<float4*>(&out[(size_t)(b * 16 + lr) * 1024 + sl]) = res;
}

// ---------------------------------------------------------------- launcher
extern "C" void kernel_launch(void* const* d_in, const int* in_sizes, int n_in,
                              void* d_out, int out_size, void* d_ws, size_t ws_size,
                              hipStream_t stream) {
  (void)in_sizes; (void)n_in; (void)out_size;
  const float* z   = (const float*)d_in[0];
  const float* rt  = (const float*)d_in[1];
  const float* dnw = (const float*)d_in[2];
  const float* dnb = (const float*)d_in[3];
  const float* lng = (const float*)d_in[4];
  const float* lnb = (const float*)d_in[5];
  const float* wq  = (const float*)d_in[6];
  const float* bq  = (const float*)d_in[7];
  const float* wk  = (const float*)d_in[8];
  const float* bk  = (const float*)d_in[9];
  const float* wv  = (const float*)d_in[10];
  const float* bv  = (const float*)d_in[11];
  const float* wo  = (const float*)d_in[12];
  const float* bo  = (const float*)d_in[13];
  const float* dcw = (const float*)d_in[14];
  const float* dcb = (const float*)d_in[15];
  float* out = (float*)d_out;

  char* p = (char*)d_ws;
  float* x            = (float*)p;          p += (size_t)M * FDEC * 4;
  unsigned short* xin = (unsigned short*)p; p += (size_t)M * KP * 2;
  unsigned short* wdn = (unsigned short*)p; p += (size_t)FDEC * KP * 2;
  unsigned short* xn  = (unsigned short*)p; p += (size_t)M * FDEC * 2;
  unsigned short* w3  = (unsigned short*)p; p += (size_t)3 * FDEC * FDEC * 2;
  float* b3           = (float*)p;          p += (size_t)3 * FDEC * 4;
  unsigned short* qkv = (unsigned short*)p; p += (size_t)M * 3 * FDEC * 2;
  unsigned short* ob  = (unsigned short*)p; p += (size_t)M * FDEC * 2;
  unsigned short* wob = (unsigned short*)p; p += (size_t)FDEC * FDEC * 2;
  unsigned short* dwb = (unsigned short*)p; p += (size_t)FD * FDEC * 2;
  if ((size_t)(p - (char*)d_ws) > ws_size) return;   // visible failure, no corruption

  k_prep_xin<<<(M * KP) / 256, 256, 0, stream>>>(z, rt, xin);
  k_cvt_pad<<<(FDEC * KP) / 256, 256, 0, stream>>>(dnw, wdn, FDEC, INK, KP);
  k_cvt_pad<<<(FDEC * FDEC) / 256, 256, 0, stream>>>(wq, w3, FDEC, FDEC, FDEC);
  k_cvt_pad<<<(FDEC * FDEC) / 256, 256, 0, stream>>>(wk, w3 + FDEC * FDEC, FDEC, FDEC, FDEC);
  k_cvt_pad<<<(FDEC * FDEC) / 256, 256, 0, stream>>>(wv, w3 + 2 * FDEC * FDEC, FDEC, FDEC, FDEC);
  k_cvt_pad<<<(FDEC * FDEC) / 256, 256, 0, stream>>>(wo, wob, FDEC, FDEC, FDEC);
  k_cvt_pad<<<(FD * FDEC) / 256, 256, 0, stream>>>(dcw, dwb, FD, FDEC, FDEC);
  k_b3<<<12, 256, 0, stream>>>(bq, bk, bv, b3);

  k_gemm<0><<<dim3(M / 128, FDEC / 128), 256, 0, stream>>>(xin, KP, wdn, KP, KP, FDEC, dnb, x, nullptr);
  k_ln<<<M, 256, 0, stream>>>(x, lng, lnb, xn);
  k_gemm<1><<<dim3(M / 128, 3 * FDEC / 128), 256, 0, stream>>>(xn, FDEC, w3, FDEC, FDEC, 3 * FDEC, b3, nullptr, qkv);
  k_attn<<<dim3(Bn * H, S / 128), 256, 0, stream>>>(qkv, ob);
  k_gemm<2><<<dim3(M / 128, FDEC / 128), 256, 0, stream>>>(ob, FDEC, wob, FDEC, FDEC, FDEC, bo, x, xn);
  k_dec<<<M / 64, 256, 0, stream>>>(xn, dwb, dcb, out);
}